// Round 4
// baseline (148.678 us; speedup 1.0000x reference)
//
#include <hip/hip_runtime.h>

// loss = 1 - mean_over_rows( all_c(real == (pred>0.5)) ), real/pred f32 [128,8192,8]
// C=8 contiguous -> one float4 = half a row. Unit-stride float4 indexing across
// the wave; halves of row k land in lanes 2k,2k+1 -> paired via ballot bits.
// Single fused kernel: per-block partials + last-block-done final reduction.

#define N_ROWS (128 * 8192)              // 1,048,576 rows
#define N_F4   (N_ROWS * 2)              // 2,097,152 float4s per input
#define BLOCK  256
#define ITERS  4
#define GRID   (N_F4 / (BLOCK * ITERS))  // 2048 blocks, exact

// Harness guarantee: d_ws is re-poisoned to 0xAA bytes before EVERY launch.
// So the done-counter deterministically starts at 0xAAAAAAAA — the block whose
// atomicAdd returns POISON + GRID - 1 is the last to finish. (If poison
// semantics ever change, d_out stays 0 -> loud validation failure, not silent.)
#define POISON 0xAAAAAAAAu

__global__ __launch_bounds__(BLOCK) void row_match_loss(
    const float4* __restrict__ real4,
    const float4* __restrict__ pred4,
    unsigned int* __restrict__ partials,   // [GRID]
    unsigned int* __restrict__ done_cnt,   // [1], starts at POISON
    float* __restrict__ out) {
  const int base = blockIdx.x * (BLOCK * ITERS) + threadIdx.x;

  // 8 independent coalesced 16B loads in flight before any use.
  float4 r[ITERS], p[ITERS];
#pragma unroll
  for (int j = 0; j < ITERS; ++j) r[j] = real4[base + j * BLOCK];
#pragma unroll
  for (int j = 0; j < ITERS; ++j) p[j] = pred4[base + j * BLOCK];

  unsigned int cnt = 0;
#pragma unroll
  for (int j = 0; j < ITERS; ++j) {
    // real is exactly 0/1: (real == (pred>0.5)) <=> ((real>0.5)==(pred>0.5))
    bool ok = ((r[j].x > 0.5f) == (p[j].x > 0.5f)) &&
              ((r[j].y > 0.5f) == (p[j].y > 0.5f)) &&
              ((r[j].z > 0.5f) == (p[j].z > 0.5f)) &&
              ((r[j].w > 0.5f) == (p[j].w > 0.5f));
    // 64-bit wave ballot: bit i = lane i's half-row ok. Row ok = both halves ok.
    unsigned long long m = __ballot(ok);
    m &= (m >> 1);
    m &= 0x5555555555555555ULL;
    cnt += (unsigned int)__popcll(m);  // wave-uniform rows-matched this iter
  }

  // Combine the block's 4 waves; publish one partial per block (max 512 < POISON).
  __shared__ unsigned int wsum[BLOCK / 64];
  const int lane = threadIdx.x & 63;
  const int wave = threadIdx.x >> 6;
  if (lane == 0) wsum[wave] = cnt;
  __syncthreads();

  __shared__ bool is_last;
  if (threadIdx.x == 0) {
    partials[blockIdx.x] = wsum[0] + wsum[1] + wsum[2] + wsum[3];
    __threadfence();  // release: partial visible device-wide before the ticket
    unsigned int ticket = atomicAdd(done_cnt, 1u);
    is_last = (ticket == POISON + (unsigned int)GRID - 1u);
  }
  __syncthreads();

  // Last-finished block reduces all partials (8 KB, L2-hot).
  if (is_last) {
    __threadfence();  // acquire: see every block's partial
    const int t = threadIdx.x;
    unsigned int s = 0;
#pragma unroll
    for (int k = 0; k < GRID / BLOCK; ++k) s += partials[t + k * BLOCK];
#pragma unroll
    for (int off = 32; off > 0; off >>= 1) s += __shfl_down(s, off, 64);
    if (lane == 0) wsum[wave] = s;
    __syncthreads();
    if (t == 0)
      out[0] = 1.0f - (float)(wsum[0] + wsum[1] + wsum[2] + wsum[3]) *
                          (1.0f / (float)N_ROWS);
  }
}

extern "C" void kernel_launch(void* const* d_in, const int* in_sizes, int n_in,
                              void* d_out, int out_size, void* d_ws, size_t ws_size,
                              hipStream_t stream) {
  const float4* real4 = (const float4*)d_in[0];
  const float4* pred4 = (const float4*)d_in[1];
  unsigned int* partials = (unsigned int*)d_ws;          // GRID * 4 B
  unsigned int* done_cnt = (unsigned int*)d_ws + GRID;   // 1 * 4 B, poison-start
  float* out = (float*)d_out;

  row_match_loss<<<GRID, BLOCK, 0, stream>>>(real4, pred4, partials, done_cnt, out);
}

// Round 5
// 98.888 us; speedup vs baseline: 1.5035x; 1.5035x over previous
//
#include <hip/hip_runtime.h>

// loss = 1 - mean_over_rows( all_c(real == (pred>0.5)) ), real/pred f32 [128,8192,8]
// C=8 contiguous -> one float4 = half a row. Unit-stride float4 indexing across
// the wave; halves of row k land in lanes 2k,2k+1 -> paired via ballot bits.
//
// Single dispatch, NO fences (R4 showed per-block __threadfence = L2 flush
// disaster on gfx950). Completion + total are carried in ONE packed atomic:
//   bits [0,21):  accumulated matched-row count  (total <= 2^20)
//   bits [21,32): finished-block count           (GRID = 1024 <= 2^11)
// The block whose atomicAdd sees blocks_before == GRID-1 is last and already
// holds the exact global total in (old + own contribution) — no visibility
// or ordering assumption beyond single-address atomic coherence.

#define N_ROWS (128 * 8192)              // 1,048,576 rows (= 2^20)
#define N_F4   (N_ROWS * 2)              // 2,097,152 float4s per input
#define BLOCK  256
#define ITERS  8
#define GRID   (N_F4 / (BLOCK * ITERS))  // 1024 blocks, exact
#define FIELD  (1u << 21)                // block-counter increment

// Harness guarantee (validated by R4 passing): d_ws is re-poisoned to 0xAA
// bytes before every launch -> counter deterministically starts at 0xAAAAAAAA.
// If that ever changes, d_out is never written -> loud failure, not silent.
#define POISON 0xAAAAAAAAu

__global__ __launch_bounds__(BLOCK) void row_match_loss(
    const float4* __restrict__ real4,
    const float4* __restrict__ pred4,
    unsigned int* __restrict__ count,    // [1] in d_ws, starts at POISON
    float* __restrict__ out) {
  const int base = blockIdx.x * (BLOCK * ITERS) + threadIdx.x;

  // 16 independent coalesced 16B loads in flight before any use.
  float4 r[ITERS], p[ITERS];
#pragma unroll
  for (int j = 0; j < ITERS; ++j) r[j] = real4[base + j * BLOCK];
#pragma unroll
  for (int j = 0; j < ITERS; ++j) p[j] = pred4[base + j * BLOCK];

  unsigned int cnt = 0;
#pragma unroll
  for (int j = 0; j < ITERS; ++j) {
    // real is exactly 0/1: (real == (pred>0.5)) <=> ((real>0.5)==(pred>0.5))
    bool ok = ((r[j].x > 0.5f) == (p[j].x > 0.5f)) &&
              ((r[j].y > 0.5f) == (p[j].y > 0.5f)) &&
              ((r[j].z > 0.5f) == (p[j].z > 0.5f)) &&
              ((r[j].w > 0.5f) == (p[j].w > 0.5f));
    // 64-bit wave ballot: bit i = lane i's half-row ok. Row ok = both halves ok.
    unsigned long long m = __ballot(ok);
    m &= (m >> 1);
    m &= 0x5555555555555555ULL;
    cnt += (unsigned int)__popcll(m);  // wave-uniform rows-matched this iter
  }

  // Combine the block's 4 waves (max 1024 rows/block < 2^21).
  __shared__ unsigned int wsum[BLOCK / 64];
  const int lane = threadIdx.x & 63;
  const int wave = threadIdx.x >> 6;
  if (lane == 0) wsum[wave] = cnt;
  __syncthreads();

  if (threadIdx.x == 0) {
    const unsigned int part = wsum[0] + wsum[1] + wsum[2] + wsum[3];
    // One device-scope atomic per block: rows in low field, block# in high.
    const unsigned int old = atomicAdd(count, part + FIELD);
    const unsigned int v = old - POISON;        // baseline-relative, mod 2^32
    // v = rows_before + FIELD * blocks_before; rows_before < 2^20 -> no carry.
    if ((v >> 21) == GRID - 1u) {               // we are the last block
      const unsigned int rows = (v + part) & (FIELD - 1u);  // global total
      out[0] = 1.0f - (float)rows * (1.0f / (float)N_ROWS);
    }
  }
}

extern "C" void kernel_launch(void* const* d_in, const int* in_sizes, int n_in,
                              void* d_out, int out_size, void* d_ws, size_t ws_size,
                              hipStream_t stream) {
  const float4* real4 = (const float4*)d_in[0];
  const float4* pred4 = (const float4*)d_in[1];
  unsigned int* count = (unsigned int*)d_ws;  // 4 B of scratch, poison-start
  float* out = (float*)d_out;

  row_match_loss<<<GRID, BLOCK, 0, stream>>>(real4, pred4, count, out);
}

// Round 6
// 91.559 us; speedup vs baseline: 1.6238x; 1.0800x over previous
//
#include <hip/hip_runtime.h>

// loss = 1 - mean_over_rows( all_c(real == (pred>0.5)) ), real/pred f32 [128,8192,8]
// C=8 contiguous -> one float4 = half a row. Unit-stride float4 indexing across
// the wave; halves of row k land in lanes 2k,2k+1 -> paired via ballot bits.
// Two dispatches, no fences, no atomics-to-one-line hot spot, no dependence on
// d_ws poison value (all partial slots are written every launch).
// Best-measured structure of the session (R3: 92.0 us total; kernel ~14 us vs
// ~10.5 us read floor; remaining total is fixed harness restore/poison work).

#define N_ROWS (128 * 8192)              // 1,048,576 rows
#define N_F4   (N_ROWS * 2)              // 2,097,152 float4s per input
#define BLOCK  256
#define ITERS  8
#define GRID   (N_F4 / (BLOCK * ITERS))  // 1024 blocks, exact

__global__ __launch_bounds__(BLOCK) void row_match_count(
    const float4* __restrict__ real4,
    const float4* __restrict__ pred4,
    unsigned int* __restrict__ partials) {
  const int base = blockIdx.x * (BLOCK * ITERS) + threadIdx.x;

  // Coalesced 16B loads; compiler interleaves load/compare at low VGPR count,
  // wave-level TLP provides the memory parallelism.
  float4 r[ITERS], p[ITERS];
#pragma unroll
  for (int j = 0; j < ITERS; ++j) r[j] = real4[base + j * BLOCK];
#pragma unroll
  for (int j = 0; j < ITERS; ++j) p[j] = pred4[base + j * BLOCK];

  unsigned int cnt = 0;
#pragma unroll
  for (int j = 0; j < ITERS; ++j) {
    // real is exactly 0/1: (real == (pred>0.5)) <=> ((real>0.5)==(pred>0.5))
    bool ok = ((r[j].x > 0.5f) == (p[j].x > 0.5f)) &&
              ((r[j].y > 0.5f) == (p[j].y > 0.5f)) &&
              ((r[j].z > 0.5f) == (p[j].z > 0.5f)) &&
              ((r[j].w > 0.5f) == (p[j].w > 0.5f));
    // 64-bit wave ballot: bit i = lane i's half-row ok. Row ok = both halves ok.
    unsigned long long m = __ballot(ok);
    m &= (m >> 1);
    m &= 0x5555555555555555ULL;
    cnt += (unsigned int)__popcll(m);  // wave-uniform rows-matched this iter
  }

  // Combine the 4 waves of the block; one partial per block, no global atomic.
  __shared__ unsigned int wsum[BLOCK / 64];
  const int lane = threadIdx.x & 63;
  const int wave = threadIdx.x >> 6;
  if (lane == 0) wsum[wave] = cnt;
  __syncthreads();
  if (threadIdx.x == 0)
    partials[blockIdx.x] = wsum[0] + wsum[1] + wsum[2] + wsum[3];
}

__global__ __launch_bounds__(256) void finalize_loss(
    const unsigned int* __restrict__ partials, float* __restrict__ out) {
  const int t = threadIdx.x;
  unsigned int s = 0;
#pragma unroll
  for (int k = 0; k < GRID / 256; ++k) s += partials[t + k * 256];  // 4 coalesced loads
#pragma unroll
  for (int off = 32; off > 0; off >>= 1) s += __shfl_down(s, off, 64);

  __shared__ unsigned int wsum[4];
  if ((t & 63) == 0) wsum[t >> 6] = s;
  __syncthreads();
  if (t == 0)
    out[0] = 1.0f - (float)(wsum[0] + wsum[1] + wsum[2] + wsum[3]) *
                        (1.0f / (float)N_ROWS);
}

extern "C" void kernel_launch(void* const* d_in, const int* in_sizes, int n_in,
                              void* d_out, int out_size, void* d_ws, size_t ws_size,
                              hipStream_t stream) {
  const float4* real4 = (const float4*)d_in[0];
  const float4* pred4 = (const float4*)d_in[1];
  unsigned int* partials = (unsigned int*)d_ws;  // GRID * 4 B = 4 KB scratch
  float* out = (float*)d_out;

  // Every partial slot is written by its block -> no memset node needed.
  row_match_count<<<GRID, BLOCK, 0, stream>>>(real4, pred4, partials);
  finalize_loss<<<1, 256, 0, stream>>>(partials, out);
}